// Round 13
// baseline (139.737 us; speedup 1.0000x reference)
//
#include <hip/hip_runtime.h>
#include <hip/hip_bf16.h>

#define D_MODEL 1024
#define T_SEQ   2048
#define BATCH   2
#define NHEADS  16
#define HDIM    64
#define QKVSZ   (BATCH * NHEADS * T_SEQ * HDIM)   // elems per Q/K/V matrix

// 0.125 * log2(e): folded into Q so softmax is pure exp2
#define SCALE_Q 0.18033688011112042f

typedef __bf16 bf16_t;
typedef bf16_t bf16x8  __attribute__((ext_vector_type(8)));
typedef float  f32x4   __attribute__((ext_vector_type(4)));
typedef float  f32x16  __attribute__((ext_vector_type(16)));
typedef unsigned uint32x4 __attribute__((ext_vector_type(4)));

#if __has_builtin(__builtin_amdgcn_exp2f)
#define EXP2F(x) __builtin_amdgcn_exp2f(x)
#else
#define EXP2F(x) exp2f(x)
#endif

__device__ __forceinline__ unsigned short f2bf(float f) {
    union { float f; unsigned u; } v; v.f = f;
    unsigned u = v.u;
    u += 0x7FFFu + ((u >> 16) & 1u);   // RNE
    return (unsigned short)(u >> 16);
}

// pack two f32 -> one u32 of 2 bf16 (lo = a, hi = b)
__device__ __forceinline__ unsigned pkbf(float a, float b) {
    unsigned r;
    asm("v_cvt_pk_bf16_f32 %0, %1, %2" : "=v"(r) : "v"(a), "v"(b));
    return r;
}

// async global->LDS, 16B per lane; LDS dest wave-uniform base (HW adds lane*16)
__device__ __forceinline__ void gload16(const unsigned short* g, unsigned short* l) {
    __builtin_amdgcn_global_load_lds(
        (const __attribute__((address_space(1))) void*)g,
        (__attribute__((address_space(3))) void*)l,
        16, 0, 0);
}

// ---------------- f32 -> bf16 convert (vectorized) ----------------
__global__ void cvt_f32_bf16(const float* __restrict__ src,
                             unsigned short* __restrict__ dst, int n4) {
    int i = blockIdx.x * blockDim.x + threadIdx.x;
    if (i < n4) {
        float4 v = reinterpret_cast<const float4*>(src)[i];
        ushort4 o;
        o.x = f2bf(v.x); o.y = f2bf(v.y); o.z = f2bf(v.z); o.w = f2bf(v.w);
        reinterpret_cast<ushort4*>(dst)[i] = o;
    }
}

// ---------------- f32 [K][N] -> bf16 [N][K] transpose-convert ----------------
__global__ __launch_bounds__(256) void cvt_transpose(
    const float* __restrict__ src, unsigned short* __restrict__ dst, int K, int N)
{
    __shared__ unsigned short Ls[64][72];
    const int n0 = blockIdx.x * 64, k0 = blockIdx.y * 64;
    const int tid = threadIdx.x;
    #pragma unroll
    for (int it = 0; it < 4; ++it) {
        const int r = it * 16 + (tid >> 4);
        const int c = (tid & 15) * 4;
        float4 v = *reinterpret_cast<const float4*>(src + (size_t)(k0 + r) * N + n0 + c);
        Ls[c + 0][r] = f2bf(v.x); Ls[c + 1][r] = f2bf(v.y);
        Ls[c + 2][r] = f2bf(v.z); Ls[c + 3][r] = f2bf(v.w);
    }
    __syncthreads();
    #pragma unroll
    for (int it = 0; it < 2; ++it) {
        const int rn = it * 32 + (tid >> 3);
        const int ck = (tid & 7) * 8;
        *reinterpret_cast<uint4*>(dst + (size_t)(n0 + rn) * K + k0 + ck) =
            *reinterpret_cast<const uint4*>(&Ls[rn][ck]);
    }
}

// ------ bf16 [b,h][T][Hd] -> sigma-permuted [b,h][Hd][T] transpose ------
// Position pos within each 64-key tile holds key sigma(pos):
//   pos = 16a + 8h + jj  ->  key = 32(a>>1) + 16(a&1) + 4h + 8(jj>>2) + (jj&3)
// so PV's B-frag can use P's native register order (no lane exchange).
__global__ __launch_bounds__(256) void transpose_v(
    const unsigned short* __restrict__ v, unsigned short* __restrict__ vt)
{
    __shared__ unsigned short Ls[64][72];
    const int t0 = blockIdx.x * 64;
    const size_t base = ((size_t)(blockIdx.z * NHEADS + blockIdx.y)) * T_SEQ * HDIM;
    const int tid = threadIdx.x;
    const int r  = tid >> 2;          // t-local 0..63
    const int c0 = (tid & 3) * 16;    // hd 0,16,32,48
    unsigned short tmp[16];
    *reinterpret_cast<uint4*>(&tmp[0]) =
        *reinterpret_cast<const uint4*>(v + base + (size_t)(t0 + r) * HDIM + c0);
    *reinterpret_cast<uint4*>(&tmp[8]) =
        *reinterpret_cast<const uint4*>(v + base + (size_t)(t0 + r) * HDIM + c0 + 8);
    #pragma unroll
    for (int i = 0; i < 16; ++i) Ls[c0 + i][r] = tmp[i];
    __syncthreads();
    const int rn = tid >> 2;          // hd 0..63
    const int ck = (tid & 3) * 16;    // pos base (multiple of 16 -> a uniform)
    const int a  = ck >> 4;
    const int kb = 32 * (a >> 1) + 16 * (a & 1);
    unsigned short buf[16];
    #pragma unroll
    for (int i = 0; i < 16; ++i) {
        const int key = kb + 4 * (i >> 3) + 8 * ((i & 7) >> 2) + (i & 3);
        buf[i] = Ls[rn][key];
    }
    *reinterpret_cast<uint4*>(vt + base + (size_t)rn * T_SEQ + t0 + ck) =
        *reinterpret_cast<const uint4*>(&buf[0]);
    *reinterpret_cast<uint4*>(vt + base + (size_t)rn * T_SEQ + t0 + ck + 8) =
        *reinterpret_cast<const uint4*>(&buf[8]);
}

// ------- 128x128-tile bf16 GEMM, BK=64, depth-2 counted-vmcnt pipeline ---------
// T3+T4: loads for tile kt+2 issued at iter kt, waited with vmcnt(8) at iter kt+1
// (only tile kt+1's 8 FIFO-oldest) -> main loop never drains vmcnt to 0.
// Cross-wave LDS visibility: each wave passes its OWN vmcnt before the barrier,
// so after the barrier ALL waves' loads for the next tile have landed.
// Swizzle: 128B rows, chunk ^= row&7 (both sides). T1 XCD remap (nwg%8==0).
template<int MODE>
__global__ __launch_bounds__(256) void gemm128(
    const unsigned short* __restrict__ A,
    const unsigned short* __restrict__ BT,
    const float* __restrict__ bias,
    unsigned short* __restrict__ qkv,
    float* __restrict__ outf,
    int M, int N, int K)
{
    __shared__ unsigned short As[2][128 * 64];
    __shared__ unsigned short Bs[2][128 * 64];
    const int tid = threadIdx.x, wv = tid >> 6, lane = tid & 63;
    const int wr = wv >> 1, wc = wv & 1;

    // T1 XCD-bijective remap
    const int P    = blockIdx.x;
    const int nwg  = gridDim.x;
    const int per  = nwg >> 3;             // tiles per XCD
    const int L    = (P & 7) * per + (P >> 3);
    const int mt   = M >> 7;               // number of M tiles
    const int m0   = (L % mt) * 128;
    const int n0   = (L / mt) * 128;

    const int srow = lane >> 3;            // staging row-within-8
    const int sch  = lane & 7;             // staging chunk

    // stage K-tile kt (64 wide) of A and B into buffer bf: 8 gload16/thread
    #define GSTAGE(kt, bf)                                                      \
        {                                                                       \
            _Pragma("unroll")                                                   \
            for (int i = 0; i < 4; ++i) {                                       \
                const int row = 32 * wv + 8 * i + srow;                         \
                const int sc  = sch ^ (row & 7);                                \
                gload16(A  + (size_t)(m0 + row) * K + (kt) * 64 + sc * 8,       \
                        &As[bf][(32 * wv + 8 * i) * 64]);                       \
                gload16(BT + (size_t)(n0 + row) * K + (kt) * 64 + sc * 8,       \
                        &Bs[bf][(32 * wv + 8 * i) * 64]);                       \
            }                                                                   \
        }
    #define VMCNT8  asm volatile("s_waitcnt vmcnt(8)" ::: "memory")
    #define VMCNT0  asm volatile("s_waitcnt vmcnt(0)" ::: "memory")
    #define LGKM0   asm volatile("s_waitcnt lgkmcnt(0)" ::: "memory")

    f32x4 acc[4][4] = {};

    GSTAGE(0, 0);
    GSTAGE(1, 1);
    VMCNT8;                                  // tile 0 (own 8 oldest) landed
    __builtin_amdgcn_s_barrier();            // -> tile 0 visible block-wide

    const int nk = K >> 6;                   // 16 K-tiles
    for (int kt = 0; kt < nk; ++kt) {
        const int cur = kt & 1;

        #pragma unroll
        for (int kk = 0; kk < 2; ++kk) {
            bf16x8 af[4], bfr[4];
            #pragma unroll
            for (int m = 0; m < 4; ++m) {
                const int row = 64 * wr + 16 * m + (lane & 15);
                const int c   = (4 * kk + (lane >> 4)) ^ (row & 7);
                af[m] = *reinterpret_cast<const bf16x8*>(&As[cur][row * 64 + c * 8]);
            }
            #pragma unroll
            for (int n = 0; n < 4; ++n) {
                const int row = 64 * wc + 16 * n + (lane & 15);
                const int c   = (4 * kk + (lane >> 4)) ^ (row & 7);
                bfr[n] = *reinterpret_cast<const bf16x8*>(&Bs[cur][row * 64 + c * 8]);
            }
            __builtin_amdgcn_s_setprio(1);
            #pragma unroll
            for (int m = 0; m < 4; ++m)
                #pragma unroll
                for (int n = 0; n < 4; ++n)
                    acc[m][n] = __builtin_amdgcn_mfma_f32_16x16x32_bf16(af[m], bfr[n], acc[m][n], 0, 0, 0);
            __builtin_amdgcn_s_setprio(0);
        }

        LGKM0;                               // all reads of buf[cur] retired
        __builtin_amdgcn_s_barrier();        // barrier1: safe to overwrite buf[cur]
        if (kt + 2 < nk) {                   // uniform condition
            GSTAGE(kt + 2, cur);             // refill buf[cur] for tile kt+2
            VMCNT8;                          // own tile-(kt+1) loads landed
        } else {
            VMCNT0;
        }
        __builtin_amdgcn_s_barrier();        // barrier2: everyone's kt+1 loads visible
    }
    #undef GSTAGE

    const int rb = m0 + 64 * wr + ((lane >> 4) << 2);
    const int cb = n0 + 64 * wc + (lane & 15);
    #pragma unroll
    for (int n = 0; n < 4; ++n) {
        const int c = cb + 16 * n;
        const float bc = bias[c];
        #pragma unroll
        for (int m = 0; m < 4; ++m) {
            #pragma unroll
            for (int jr = 0; jr < 4; ++jr) {
                const int r = rb + 16 * m + jr;
                float val = acc[m][n][jr] + bc;
                if (MODE == 0) {
                    const int which = c >> 10;
                    const int rem = c & 1023;
                    const int h = rem >> 6, hd = rem & 63;
                    const int b = r >> 11, t = r & 2047;
                    if (which == 0) val *= SCALE_Q;
                    qkv[(size_t)which * QKVSZ + ((((size_t)b * NHEADS + h) * T_SEQ + t) << 6) + hd] = f2bf(val);
                } else {
                    outf[(size_t)r * N + c] = val;
                }
            }
        }
    }
}

// ---------------- flash attention, KV-split 8-wave blocks (R10 artifact) --------
// + T1 XCD-bijective remap (each XCD owns 4 whole heads) + T5 setprio.
__global__ __launch_bounds__(512) void attn32(
    const unsigned short* __restrict__ qb,
    const unsigned short* __restrict__ kb,
    const unsigned short* __restrict__ vtb,
    unsigned short* __restrict__ ctx)   // [B][T][D] bf16
{
    __shared__ unsigned short Ks[2][2][64 * 64];   // [group][buf][key][hd]
    __shared__ unsigned short Vt[2][2][64 * 64];   // [group][buf][hd][pos]

    const int tid = threadIdx.x;
    const int wv = tid >> 6, lane = tid & 63;
    const int wg = wv >> 2, wl = wv & 3;
    const int ql = lane & 31;
    const int hi = lane >> 5;

    // XCD-bijective remap of the 512-block grid: P -> (qt, head-index)
    const int P    = blockIdx.x + 16 * blockIdx.y + 256 * blockIdx.z;
    const int xcd  = P & 7, slot = P >> 3;
    const int qt   = slot & 15;
    const int hidx = xcd * 4 + (slot >> 4);
    const int h    = hidx & 15, b = hidx >> 4;

    const size_t base = ((size_t)(b * NHEADS + h)) * T_SEQ * HDIM;
    const unsigned short* Kp  = kb  + base;
    const unsigned short* Vtp = vtb + base;   // [hd][t], permuted key axis
    const unsigned short* Qp  = qb  + base + ((size_t)qt * 128 + wl * 32 + ql) * HDIM;

    // Q B-fragments: chunk c covers hd = 16c + 8hi + j
    const bf16x8 qf0 = *reinterpret_cast<const bf16x8*>(Qp + 0  + hi * 8);
    const bf16x8 qf1 = *reinterpret_cast<const bf16x8*>(Qp + 16 + hi * 8);
    const bf16x8 qf2 = *reinterpret_cast<const bf16x8*>(Qp + 32 + hi * 8);
    const bf16x8 qf3 = *reinterpret_cast<const bf16x8*>(Qp + 48 + hi * 8);

    // staging: group's 4 waves stage its 64-row tile (8 chunks of 8 rows)
    const int srow = lane >> 3;
    const int ssl  = lane & 7;
    #define STAGE(i, bf)                                                          \
        {                                                                         \
            _Pragma("unroll")                                                     \
            for (int ihalf = 0; ihalf < 2; ++ihalf) {                             \
                const int g2  = wl * 2 + ihalf;                                   \
                const int row = 8 * g2 + srow;                                    \
                const int sl  = ssl ^ (row & 7) ^ ((row >> 3) & 3);               \
                gload16(Kp  + (size_t)((wg * 16 + (i)) * 64 + row) * HDIM + sl * 8, \
                        &Ks[wg][bf][g2 * 512]);                                   \
                gload16(Vtp + (size_t)row * T_SEQ + (wg * 16 + (i)) * 64 + sl * 8, \
                        &Vt[wg][bf][g2 * 512]);                                   \
            }                                                                     \
        }

    STAGE(0, 0);
    __syncthreads();

    const int kx = (ql & 7) ^ ((ql >> 3) & 3);   // row-XOR term for frag reads

    float m = -1e30f, l = 0.f;
    f32x16 o0 = {}, o1 = {};

    for (int i = 0; i < 16; ++i) {
        const int cur = i & 1;
        if (i + 1 < 16) STAGE(i + 1, cur ^ 1);

        // ---- S^T = K Q : s0 = keys 0-31, s1 = keys 32-63 (col=q, row=key) ----
        f32x16 s0 = {}, s1 = {};
        __builtin_amdgcn_s_setprio(1);
        #pragma unroll
        for (int c = 0; c < 4; ++c) {
            const int sw = (2 * c + hi) ^ kx;
            const bf16x8 k0 = *reinterpret_cast<const bf16x8*>(&Ks[wg][cur][(ql)      * 64 + sw * 8]);
            const bf16x8 k1 = *reinterpret_cast<const bf16x8*>(&Ks[wg][cur][(32 + ql) * 64 + sw * 8]);
            const bf16x8 qc = (c == 0) ? qf0 : (c == 1) ? qf1 : (c == 2) ? qf2 : qf3;
            s0 = __builtin_amdgcn_mfma_f32_32x32x16_bf16(k0, qc, s0, 0, 0, 0);
            s1 = __builtin_amdgcn_mfma_f32_32x32x16_bf16(k1, qc, s1, 0, 0, 0);
        }
        __builtin_amdgcn_s_setprio(0);

        // ---- row max (tree, 4 chains) + cross-half shuffle ----
        float a0 = fmaxf(s0[0], s0[4]), a1 = fmaxf(s0[1], s0[5]);
        float a2 = fmaxf(s0[2], s0[6]), a3 = fmaxf(s0[3], s0[7]);
        a0 = fmaxf(a0, fmaxf(s0[8],  s0[12]));  a1 = fmaxf(a1, fmaxf(s0[9],  s0[13]));
        a2 = fmaxf(a2, fmaxf(s0[10], s0[14])); a3 = fmaxf(a3, fmaxf(s0[11], s0[15]));
        a0 = fmaxf(a0, fmaxf(s1[0], s1[4]));   a1 = fmaxf(a1, fmaxf(s1[1], s1[5]));
        a2 = fmaxf(a2, fmaxf(s1[2], s1[6]));   a3 = fmaxf(a3, fmaxf(s1[3], s1[7]));
        a0 = fmaxf(a0, fmaxf(s1[8],  s1[12])); a1 = fmaxf(a1, fmaxf(s1[9],  s1[13]));
        a2 = fmaxf(a2, fmaxf(s1[10], s1[14])); a3 = fmaxf(a3, fmaxf(s1[11], s1[15]));
        float mx = fmaxf(fmaxf(a0, a1), fmaxf(a2, a3));
        mx = fmaxf(mx, __shfl_xor(mx, 32));

        // ---- defer-max rescale (THR = 8 in log2 units) ----
        if (__any(mx > m + 8.0f)) {
            const float mn = fmaxf(m, mx);
            const float sc = EXP2F(m - mn);
            l *= sc; m = mn;
            #pragma unroll
            for (int r = 0; r < 16; ++r) { o0[r] *= sc; o1[r] *= sc; }
        }

        // ---- P = exp2(S - m), row sum (4 chains) ----
        #pragma unroll
        for (int r = 0; r < 16; ++r) s0[r] = EXP2F(s0[r] - m);
        #pragma unroll
        for (int r = 0; r < 16; ++r) s1[r] = EXP2F(s1[r] - m);
        float b0 = 0.f, b1 = 0.f, b2 = 0.f, b3 = 0.f;
        #pragma unroll
        for (int r = 0; r < 16; r += 4) {
            b0 += s0[r]; b1 += s0[r + 1]; b2 += s0[r + 2]; b3 += s0[r + 3];
            b0 += s1[r]; b1 += s1[r + 1]; b2 += s1[r + 2]; b3 += s1[r + 3];
        }
        float rs = (b0 + b1) + (b2 + b3);
        l += rs + __shfl_xor(rs, 32);

        // ---- PV: P native regs ARE the B-frag (V^T sigma-permuted) ----
        __builtin_amdgcn_s_setprio(1);
        #pragma unroll
        for (int kc = 0; kc < 4; ++kc) {
            uint32x4 fw;
            if (kc == 0) {
                fw.x = pkbf(s0[0], s0[1]);   fw.y = pkbf(s0[2], s0[3]);
                fw.z = pkbf(s0[4], s0[5]);   fw.w = pkbf(s0[6], s0[7]);
            } else if (kc == 1) {
                fw.x = pkbf(s0[8], s0[9]);   fw.y = pkbf(s0[10], s0[11]);
                fw.z = pkbf(s0[12], s0[13]); fw.w = pkbf(s0[14], s0[15]);
            } else if (kc == 2) {
                fw.x = pkbf(s1[0], s1[1]);   fw.y = pkbf(s1[2], s1[3]);
                fw.z = pkbf(s1[4], s1[5]);   fw.w = pkbf(s1[6], s1[7]);
            } else {
                fw.x = pkbf(s1[8], s1[9]);   fw.y = pkbf(s1[10], s1[11]);
                fw.z = pkbf(s1[12], s1[13]); fw.w = pkbf(s1[14], s1[15]);
            }
            const bf16x8 pa = __builtin_bit_cast(bf16x8, fw);
            const int sw = (2 * kc + hi) ^ kx;
            const bf16x8 vva = *reinterpret_cast<const bf16x8*>(&Vt[wg][cur][(ql)      * 64 + sw * 8]);
            const bf16x8 vvb = *reinterpret_cast<const bf16x8*>(&Vt[wg][cur][(32 + ql) * 64 + sw * 8]);
            o0 = __builtin_amdgcn_mfma_f32_32x32x16_bf16(vva, pa, o0, 0, 0, 0);
            o1 = __builtin_amdgcn_mfma_f32_32x32x16_bf16(vvb, pa, o1, 0, 0, 0);
        }
        __builtin_amdgcn_s_setprio(0);

        __syncthreads();   // drains prefetch vmcnt + fences buffer reuse
    }
    #undef STAGE

    // ---- merge the two KV groups via LDS (padded strides: no bank conflicts) ----
    float* xo0  = (float*)&Ks[0][0][0];   // 256 x 17 f32 (o0)
    float* xo1m = (float*)&Vt[0][0][0];   // 256 x 19 f32 (o1, m, l)
    const int idx = wl * 64 + lane;
    if (wg == 1) {
        float* pa0 = xo0 + idx * 17;
        float* pb0 = xo1m + idx * 19;
        #pragma unroll
        for (int r = 0; r < 16; ++r) pa0[r] = o0[r];
        #pragma unroll
        for (int r = 0; r < 16; ++r) pb0[r] = o1[r];
        pb0[16] = m; pb0[17] = l;
    }
    __syncthreads();
    if (wg == 0) {
        const float* pa0 = xo0 + idx * 17;
        const float* pb0 = xo1m + idx * 19;
        const float m2 = pb0[16], l2 = pb0[17];
        const float mn = fmaxf(m, m2);
        const float ca = EXP2F(m - mn), cb = EXP2F(m2 - mn);
        const float invl = 1.0f / (l * ca + l2 * cb);
        const float fa = ca * invl, fb = cb * invl;

        const int t = qt * 128 + wl * 32 + ql;
        unsigned short* crow = ctx + ((size_t)b * T_SEQ + t) * D_MODEL + h * HDIM;
        #pragma unroll
        for (int r4 = 0; r4 < 4; ++r4) {
            const int d0 = 8 * r4 + 4 * hi;
            ushort4 w;
            w.x = f2bf(o0[4 * r4 + 0] * fa + pa0[4 * r4 + 0] * fb);
            w.y = f2bf(o0[4 * r4 + 1] * fa + pa0[4 * r4 + 1] * fb);
            w.z = f2bf(o0[4 * r4 + 2] * fa + pa0[4 * r4 + 2] * fb);
            w.w = f2bf(o0[4 * r4 + 3] * fa + pa0[4 * r4 + 3] * fb);
            *reinterpret_cast<ushort4*>(crow + d0) = w;
            w.x = f2bf(o1[4 * r4 + 0] * fa + pb0[4 * r4 + 0] * fb);
            w.y = f2bf(o1[4 * r4 + 1] * fa + pb0[4 * r4 + 1] * fb);
            w.z = f2bf(o1[4 * r4 + 2] * fa + pb0[4 * r4 + 2] * fb);
            w.w = f2bf(o1[4 * r4 + 3] * fa + pb0[4 * r4 + 3] * fb);
            *reinterpret_cast<ushort4*>(crow + 32 + d0) = w;
        }
    }
}

extern "C" void kernel_launch(void* const* d_in, const int* in_sizes, int n_in,
                              void* d_out, int out_size, void* d_ws, size_t ws_size,
                              hipStream_t stream) {
    const float* x    = (const float*)d_in[0];
    const float* Wqkv = (const float*)d_in[1];
    const float* bqkv = (const float*)d_in[2];
    const float* Wout = (const float*)d_in[3];
    const float* bout = (const float*)d_in[4];
    float* out = (float*)d_out;

    char* ws = (char*)d_ws;
    unsigned short* xb    = (unsigned short*)(ws);                 // 8 MB; reused as V^T
    unsigned short* wqkvT = (unsigned short*)(ws + 8388608);       // 6 MB  [3072][1024]
    unsigned short* woutT = (unsigned short*)(ws + 14680064);      // 2 MB  [1024][1024]
    unsigned short* qkv   = (unsigned short*)(ws + 16777216);      // 24 MB (Q, K, V)
    unsigned short* ctx   = (unsigned short*)(ws + 41943040);      // 8 MB

    int n4 = (BATCH * T_SEQ * D_MODEL) / 4;
    cvt_f32_bf16<<<(n4 + 255) / 256, 256, 0, stream>>>(x, xb, n4);

    dim3 gt1(3 * D_MODEL / 64, D_MODEL / 64);
    cvt_transpose<<<gt1, 256, 0, stream>>>(Wqkv, wqkvT, D_MODEL, 3 * D_MODEL);
    dim3 gt2(D_MODEL / 64, D_MODEL / 64);
    cvt_transpose<<<gt2, 256, 0, stream>>>(Wout, woutT, D_MODEL, D_MODEL);

    // gemm0: 1-D grid, (N/128)*(M/128) = 24*32 = 768 blocks (%8==0)
    gemm128<0><<<768, 256, 0, stream>>>(xb, wqkvT, bqkv, qkv, nullptr,
                                        BATCH * T_SEQ, 3 * D_MODEL, D_MODEL);

    // V [b][h][t][hd] -> sigma-permuted V^T [b][h][hd][t], into xb (dead after gemm0)
    dim3 gtv(T_SEQ / 64, NHEADS, BATCH);
    transpose_v<<<gtv, 256, 0, stream>>>(qkv + (size_t)2 * QKVSZ, xb);

    dim3 g2(T_SEQ / 128, NHEADS, BATCH);
    attn32<<<g2, 512, 0, stream>>>(qkv,
                                   qkv + (size_t)QKVSZ,
                                   xb,
                                   ctx);

    // gemm1: 1-D grid, (N/128)*(M/128) = 8*32 = 256 blocks (%8==0)
    gemm128<1><<<256, 256, 0, stream>>>(ctx, woutT, bout, nullptr, out,
                                        BATCH * T_SEQ, D_MODEL, D_MODEL);
}

// Round 15
// 120.747 us; speedup vs baseline: 1.1573x; 1.1573x over previous
//
#include <hip/hip_runtime.h>
#include <hip/hip_bf16.h>

#define D_MODEL 1024
#define T_SEQ   2048
#define BATCH   2
#define NHEADS  16
#define HDIM    64
#define QKVSZ   (BATCH * NHEADS * T_SEQ * HDIM)   // elems per Q/K/V matrix

// 0.125 * log2(e): folded into Q so softmax is pure exp2
#define SCALE_Q 0.18033688011112042f

typedef __bf16 bf16_t;
typedef bf16_t bf16x8  __attribute__((ext_vector_type(8)));
typedef float  f32x4   __attribute__((ext_vector_type(4)));
typedef float  f32x16  __attribute__((ext_vector_type(16)));
typedef unsigned uint32x4 __attribute__((ext_vector_type(4)));

#if __has_builtin(__builtin_amdgcn_exp2f)
#define EXP2F(x) __builtin_amdgcn_exp2f(x)
#else
#define EXP2F(x) exp2f(x)
#endif

__device__ __forceinline__ unsigned short f2bf(float f) {
    union { float f; unsigned u; } v; v.f = f;
    unsigned u = v.u;
    u += 0x7FFFu + ((u >> 16) & 1u);   // RNE
    return (unsigned short)(u >> 16);
}

// pack two f32 -> one u32 of 2 bf16 (lo = a, hi = b)
__device__ __forceinline__ unsigned pkbf(float a, float b) {
    unsigned r;
    asm("v_cvt_pk_bf16_f32 %0, %1, %2" : "=v"(r) : "v"(a), "v"(b));
    return r;
}

// async global->LDS, 16B per lane; LDS dest wave-uniform base (HW adds lane*16)
__device__ __forceinline__ void gload16(const unsigned short* g, unsigned short* l) {
    __builtin_amdgcn_global_load_lds(
        (const __attribute__((address_space(1))) void*)g,
        (__attribute__((address_space(3))) void*)l,
        16, 0, 0);
}

// ---------------- fused prep: cvt x + transpose-convert Wqkv, Wout --------------
// blocks [0,4096): x f32->bf16 (float4/thread; 4096*256 = 1048576 float4s = B*T*D)
// blocks [4096,4864): Wqkv [1024][3072] -> wqkvT [3072][1024] bf16
// blocks [4864,5120): Wout [1024][1024] -> woutT [1024][1024] bf16
__global__ __launch_bounds__(256) void prep(
    const float* __restrict__ x,    unsigned short* __restrict__ xb,
    const float* __restrict__ Wqkv, unsigned short* __restrict__ wqkvT,
    const float* __restrict__ Wout, unsigned short* __restrict__ woutT)
{
    __shared__ unsigned short Ls[64][72];
    const int blk = blockIdx.x;
    const int tid = threadIdx.x;

    if (blk < 4096) {
        const int i = blk * 256 + tid;      // < 1048576 = (B*T_SEQ*D_MODEL)/4
        float4 v = reinterpret_cast<const float4*>(x)[i];
        ushort4 o;
        o.x = f2bf(v.x); o.y = f2bf(v.y); o.z = f2bf(v.z); o.w = f2bf(v.w);
        reinterpret_cast<ushort4*>(xb)[i] = o;
        return;
    }

    const float* src;
    unsigned short* dst;
    int n0, k0, N;
    if (blk < 4864) {
        const int idx = blk - 4096;         // 48 x 16
        n0 = (idx % 48) * 64; k0 = (idx / 48) * 64;
        src = Wqkv; dst = wqkvT; N = 3 * D_MODEL;
    } else {
        const int idx = blk - 4864;         // 16 x 16
        n0 = (idx % 16) * 64; k0 = (idx / 16) * 64;
        src = Wout; dst = woutT; N = D_MODEL;
    }
    const int K = D_MODEL;
    #pragma unroll
    for (int it = 0; it < 4; ++it) {
        const int r = it * 16 + (tid >> 4);
        const int c = (tid & 15) * 4;
        float4 v = *reinterpret_cast<const float4*>(src + (size_t)(k0 + r) * N + n0 + c);
        Ls[c + 0][r] = f2bf(v.x); Ls[c + 1][r] = f2bf(v.y);
        Ls[c + 2][r] = f2bf(v.z); Ls[c + 3][r] = f2bf(v.w);
    }
    __syncthreads();
    #pragma unroll
    for (int it = 0; it < 2; ++it) {
        const int rn = it * 32 + (tid >> 3);
        const int ck = (tid & 7) * 8;
        *reinterpret_cast<uint4*>(dst + (size_t)(n0 + rn) * K + k0 + ck) =
            *reinterpret_cast<const uint4*>(&Ls[rn][ck]);
    }
}

// ---------------- 128x128-tile bf16 GEMM, double-buffered (R12 artifact) --------
// T1 XCD remap (1-D grid, nwg % 8 == 0; each XCD owns a contiguous chunk).
// MODE 0: Q (pre-scaled) and K as [b][h][t][hd]; V written DIRECTLY as
//   sigma-permuted V^T [b][h][hd][pos] (pos = sigma^-1(t) within each 64-tile):
//   the accumulator's 4-row jr-run (t 4-aligned) maps to a 4-aligned pos run,
//   so each (m,n) packs into one ushort4 store. Values bit-identical to the
//   old transpose_v output. MODE 1: f32 out + bias.
template<int MODE>
__global__ __launch_bounds__(256) void gemm128(
    const unsigned short* __restrict__ A,
    const unsigned short* __restrict__ BT,
    const float* __restrict__ bias,
    unsigned short* __restrict__ qkv,
    float* __restrict__ outf,
    int M, int N, int K)
{
    __shared__ unsigned short As[2][128 * 32];
    __shared__ unsigned short Bs[2][128 * 32];
    const int tid = threadIdx.x, wv = tid >> 6, lane = tid & 63;
    const int wr = wv >> 1, wc = wv & 1;

    // T1 XCD-bijective remap
    const int P    = blockIdx.x;
    const int nwg  = gridDim.x;
    const int per  = nwg >> 3;             // tiles per XCD
    const int L    = (P & 7) * per + (P >> 3);
    const int mt   = M >> 7;               // number of M tiles
    const int m0   = (L % mt) * 128;
    const int n0   = (L / mt) * 128;

    const int srow0 = 32 * wv + (lane >> 2);
    const int skc0  = (lane & 3) ^ ((srow0 >> 1) & 3);
    const int srow1 = srow0 + 16;
    const int skc1  = (lane & 3) ^ ((srow1 >> 1) & 3);

    #define GSTAGE(k0v, bf)                                                     \
        {                                                                       \
            gload16(A  + (size_t)(m0 + srow0) * K + (k0v) + skc0 * 8,           \
                    &As[bf][(32 * wv) * 32]);                                   \
            gload16(BT + (size_t)(n0 + srow0) * K + (k0v) + skc0 * 8,           \
                    &Bs[bf][(32 * wv) * 32]);                                   \
            gload16(A  + (size_t)(m0 + srow1) * K + (k0v) + skc1 * 8,           \
                    &As[bf][(32 * wv + 16) * 32]);                              \
            gload16(BT + (size_t)(n0 + srow1) * K + (k0v) + skc1 * 8,           \
                    &Bs[bf][(32 * wv + 16) * 32]);                              \
        }

    f32x4 acc[4][4] = {};

    GSTAGE(0, 0);
    __syncthreads();

    const int nk = K >> 5;
    for (int k = 0; k < nk; ++k) {
        const int cur = k & 1;
        if (k + 1 < nk) GSTAGE((k + 1) << 5, cur ^ 1);

        bf16x8 af[4], bfr[4];
        #pragma unroll
        for (int m = 0; m < 4; ++m) {
            const int row = 64 * wr + 16 * m + (lane & 15);
            const int s   = (lane >> 4) ^ ((row >> 1) & 3);
            af[m] = *reinterpret_cast<const bf16x8*>(&As[cur][row * 32 + s * 8]);
        }
        #pragma unroll
        for (int n = 0; n < 4; ++n) {
            const int row = 64 * wc + 16 * n + (lane & 15);
            const int s   = (lane >> 4) ^ ((row >> 1) & 3);
            bfr[n] = *reinterpret_cast<const bf16x8*>(&Bs[cur][row * 32 + s * 8]);
        }
        #pragma unroll
        for (int m = 0; m < 4; ++m)
            #pragma unroll
            for (int n = 0; n < 4; ++n)
                acc[m][n] = __builtin_amdgcn_mfma_f32_16x16x32_bf16(af[m], bfr[n], acc[m][n], 0, 0, 0);
        __syncthreads();
    }
    #undef GSTAGE

    const int rb = m0 + 64 * wr + ((lane >> 4) << 2);
    const int cb = n0 + 64 * wc + (lane & 15);
    #pragma unroll
    for (int n = 0; n < 4; ++n) {
        const int c = cb + 16 * n;
        const float bc = bias[c];
        if (MODE == 0 && (c >> 10) == 2) {
            // ---- direct sigma-permuted V^T store (one ushort4 per m) ----
            const int h  = (c & 1023) >> 6;
            const int hd = c & 63;
            #pragma unroll
            for (int m = 0; m < 4; ++m) {
                const int r4  = rb + 16 * m;          // 4-aligned t-run base
                const int bb  = r4 >> 11;
                const int tw  = r4 & 2047;
                const int tile = tw >> 6;
                const int key6 = tw & 63;
                const int posb = 16 * ((((key6 >> 5) & 1) << 1) | ((key6 >> 4) & 1))
                               + 8 * ((key6 >> 2) & 1) + 4 * ((key6 >> 3) & 1);
                ushort4 w4;
                w4.x = f2bf(acc[m][n][0] + bc);
                w4.y = f2bf(acc[m][n][1] + bc);
                w4.z = f2bf(acc[m][n][2] + bc);
                w4.w = f2bf(acc[m][n][3] + bc);
                unsigned short* vt = qkv + (size_t)2 * QKVSZ
                    + ((((size_t)bb * NHEADS + h) * HDIM + hd) << 11)
                    + tile * 64 + posb;
                *reinterpret_cast<ushort4*>(vt) = w4;
            }
            continue;
        }
        #pragma unroll
        for (int m = 0; m < 4; ++m) {
            #pragma unroll
            for (int jr = 0; jr < 4; ++jr) {
                const int r = rb + 16 * m + jr;
                float val = acc[m][n][jr] + bc;
                if (MODE == 0) {
                    const int which = c >> 10;
                    const int rem = c & 1023;
                    const int h = rem >> 6, hd = rem & 63;
                    const int b = r >> 11, t = r & 2047;
                    if (which == 0) val *= SCALE_Q;
                    qkv[(size_t)which * QKVSZ + ((((size_t)b * NHEADS + h) * T_SEQ + t) << 6) + hd] = f2bf(val);
                } else {
                    outf[(size_t)r * N + c] = val;
                }
            }
        }
    }
}

// ---------------- flash attention, KV-split 8-wave blocks (R10/R12 artifact) ----
// + T1 XCD-bijective remap (each XCD owns 4 whole heads) + T5 setprio.
__global__ __launch_bounds__(512) void attn32(
    const unsigned short* __restrict__ qb,
    const unsigned short* __restrict__ kb,
    const unsigned short* __restrict__ vtb,
    unsigned short* __restrict__ ctx)   // [B][T][D] bf16
{
    __shared__ unsigned short Ks[2][2][64 * 64];   // [group][buf][key][hd]
    __shared__ unsigned short Vt[2][2][64 * 64];   // [group][buf][hd][pos]

    const int tid = threadIdx.x;
    const int wv = tid >> 6, lane = tid & 63;
    const int wg = wv >> 2, wl = wv & 3;
    const int ql = lane & 31;
    const int hi = lane >> 5;

    // XCD-bijective remap of the 512-block grid: P -> (qt, head-index)
    const int P    = blockIdx.x + 16 * blockIdx.y + 256 * blockIdx.z;
    const int xcd  = P & 7, slot = P >> 3;
    const int qt   = slot & 15;
    const int hidx = xcd * 4 + (slot >> 4);
    const int h    = hidx & 15, b = hidx >> 4;

    const size_t base = ((size_t)(b * NHEADS + h)) * T_SEQ * HDIM;
    const unsigned short* Kp  = kb  + base;
    const unsigned short* Vtp = vtb + base;   // [hd][t], permuted key axis
    const unsigned short* Qp  = qb  + base + ((size_t)qt * 128 + wl * 32 + ql) * HDIM;

    // Q B-fragments: chunk c covers hd = 16c + 8hi + j
    const bf16x8 qf0 = *reinterpret_cast<const bf16x8*>(Qp + 0  + hi * 8);
    const bf16x8 qf1 = *reinterpret_cast<const bf16x8*>(Qp + 16 + hi * 8);
    const bf16x8 qf2 = *reinterpret_cast<const bf16x8*>(Qp + 32 + hi * 8);
    const bf16x8 qf3 = *reinterpret_cast<const bf16x8*>(Qp + 48 + hi * 8);

    // staging: group's 4 waves stage its 64-row tile (8 chunks of 8 rows)
    const int srow = lane >> 3;
    const int ssl  = lane & 7;
    #define STAGE(i, bf)                                                          \
        {                                                                         \
            _Pragma("unroll")                                                     \
            for (int ihalf = 0; ihalf < 2; ++ihalf) {                             \
                const int g2  = wl * 2 + ihalf;                                   \
                const int row = 8 * g2 + srow;                                    \
                const int sl  = ssl ^ (row & 7) ^ ((row >> 3) & 3);               \
                gload16(Kp  + (size_t)((wg * 16 + (i)) * 64 + row) * HDIM + sl * 8, \
                        &Ks[wg][bf][g2 * 512]);                                   \
                gload16(Vtp + (size_t)row * T_SEQ + (wg * 16 + (i)) * 64 + sl * 8, \
                        &Vt[wg][bf][g2 * 512]);                                   \
            }                                                                     \
        }

    STAGE(0, 0);
    __syncthreads();

    const int kx = (ql & 7) ^ ((ql >> 3) & 3);   // row-XOR term for frag reads

    float m = -1e30f, l = 0.f;
    f32x16 o0 = {}, o1 = {};

    for (int i = 0; i < 16; ++i) {
        const int cur = i & 1;
        if (i + 1 < 16) STAGE(i + 1, cur ^ 1);

        // ---- S^T = K Q : s0 = keys 0-31, s1 = keys 32-63 (col=q, row=key) ----
        f32x16 s0 = {}, s1 = {};
        __builtin_amdgcn_s_setprio(1);
        #pragma unroll
        for (int c = 0; c < 4; ++c) {
            const int sw = (2 * c + hi) ^ kx;
            const bf16x8 k0 = *reinterpret_cast<const bf16x8*>(&Ks[wg][cur][(ql)      * 64 + sw * 8]);
            const bf16x8 k1 = *reinterpret_cast<const bf16x8*>(&Ks[wg][cur][(32 + ql) * 64 + sw * 8]);
            const bf16x8 qc = (c == 0) ? qf0 : (c == 1) ? qf1 : (c == 2) ? qf2 : qf3;
            s0 = __builtin_amdgcn_mfma_f32_32x32x16_bf16(k0, qc, s0, 0, 0, 0);
            s1 = __builtin_amdgcn_mfma_f32_32x32x16_bf16(k1, qc, s1, 0, 0, 0);
        }
        __builtin_amdgcn_s_setprio(0);

        // ---- row max (tree, 4 chains) + cross-half shuffle ----
        float a0 = fmaxf(s0[0], s0[4]), a1 = fmaxf(s0[1], s0[5]);
        float a2 = fmaxf(s0[2], s0[6]), a3 = fmaxf(s0[3], s0[7]);
        a0 = fmaxf(a0, fmaxf(s0[8],  s0[12]));  a1 = fmaxf(a1, fmaxf(s0[9],  s0[13]));
        a2 = fmaxf(a2, fmaxf(s0[10], s0[14])); a3 = fmaxf(a3, fmaxf(s0[11], s0[15]));
        a0 = fmaxf(a0, fmaxf(s1[0], s1[4]));   a1 = fmaxf(a1, fmaxf(s1[1], s1[5]));
        a2 = fmaxf(a2, fmaxf(s1[2], s1[6]));   a3 = fmaxf(a3, fmaxf(s1[3], s1[7]));
        a0 = fmaxf(a0, fmaxf(s1[8],  s1[12])); a1 = fmaxf(a1, fmaxf(s1[9],  s1[13]));
        a2 = fmaxf(a2, fmaxf(s1[10], s1[14])); a3 = fmaxf(a3, fmaxf(s1[11], s1[15]));
        float mx = fmaxf(fmaxf(a0, a1), fmaxf(a2, a3));
        mx = fmaxf(mx, __shfl_xor(mx, 32));

        // ---- defer-max rescale (THR = 8 in log2 units) ----
        if (__any(mx > m + 8.0f)) {
            const float mn = fmaxf(m, mx);
            const float sc = EXP2F(m - mn);
            l *= sc; m = mn;
            #pragma unroll
            for (int r = 0; r < 16; ++r) { o0[r] *= sc; o1[r] *= sc; }
        }

        // ---- P = exp2(S - m), row sum (4 chains) ----
        #pragma unroll
        for (int r = 0; r < 16; ++r) s0[r] = EXP2F(s0[r] - m);
        #pragma unroll
        for (int r = 0; r < 16; ++r) s1[r] = EXP2F(s1[r] - m);
        float b0 = 0.f, b1 = 0.f, b2 = 0.f, b3 = 0.f;
        #pragma unroll
        for (int r = 0; r < 16; r += 4) {
            b0 += s0[r]; b1 += s0[r + 1]; b2 += s0[r + 2]; b3 += s0[r + 3];
            b0 += s1[r]; b1 += s1[r + 1]; b2 += s1[r + 2]; b3 += s1[r + 3];
        }
        float rs = (b0 + b1) + (b2 + b3);
        l += rs + __shfl_xor(rs, 32);

        // ---- PV: P native regs ARE the B-frag (V^T sigma-permuted) ----
        __builtin_amdgcn_s_setprio(1);
        #pragma unroll
        for (int kc = 0; kc < 4; ++kc) {
            uint32x4 fw;
            if (kc == 0) {
                fw.x = pkbf(s0[0], s0[1]);   fw.y = pkbf(s0[2], s0[3]);
                fw.z = pkbf(s0[4], s0[5]);   fw.w = pkbf(s0[6], s0[7]);
            } else if (kc == 1) {
                fw.x = pkbf(s0[8], s0[9]);   fw.y = pkbf(s0[10], s0[11]);
                fw.z = pkbf(s0[12], s0[13]); fw.w = pkbf(s0[14], s0[15]);
            } else if (kc == 2) {
                fw.x = pkbf(s1[0], s1[1]);   fw.y = pkbf(s1[2], s1[3]);
                fw.z = pkbf(s1[4], s1[5]);   fw.w = pkbf(s1[6], s1[7]);
            } else {
                fw.x = pkbf(s1[8], s1[9]);   fw.y = pkbf(s1[10], s1[11]);
                fw.z = pkbf(s1[12], s1[13]); fw.w = pkbf(s1[14], s1[15]);
            }
            const bf16x8 pa = __builtin_bit_cast(bf16x8, fw);
            const int sw = (2 * kc + hi) ^ kx;
            const bf16x8 vva = *reinterpret_cast<const bf16x8*>(&Vt[wg][cur][(ql)      * 64 + sw * 8]);
            const bf16x8 vvb = *reinterpret_cast<const bf16x8*>(&Vt[wg][cur][(32 + ql) * 64 + sw * 8]);
            o0 = __builtin_amdgcn_mfma_f32_32x32x16_bf16(vva, pa, o0, 0, 0, 0);
            o1 = __builtin_amdgcn_mfma_f32_32x32x16_bf16(vvb, pa, o1, 0, 0, 0);
        }
        __builtin_amdgcn_s_setprio(0);

        __syncthreads();   // drains prefetch vmcnt + fences buffer reuse
    }
    #undef STAGE

    // ---- merge the two KV groups via LDS (padded strides: no bank conflicts) ----
    float* xo0  = (float*)&Ks[0][0][0];   // 256 x 17 f32 (o0)
    float* xo1m = (float*)&Vt[0][0][0];   // 256 x 19 f32 (o1, m, l)
    const int idx = wl * 64 + lane;
    if (wg == 1) {
        float* pa0 = xo0 + idx * 17;
        float* pb0 = xo1m + idx * 19;
        #pragma unroll
        for (int r = 0; r < 16; ++r) pa0[r] = o0[r];
        #pragma unroll
        for (int r = 0; r < 16; ++r) pb0[r] = o1[r];
        pb0[16] = m; pb0[17] = l;
    }
    __syncthreads();
    if (wg == 0) {
        const float* pa0 = xo0 + idx * 17;
        const float* pb0 = xo1m + idx * 19;
        const float m2 = pb0[16], l2 = pb0[17];
        const float mn = fmaxf(m, m2);
        const float ca = EXP2F(m - mn), cb = EXP2F(m2 - mn);
        const float invl = 1.0f / (l * ca + l2 * cb);
        const float fa = ca * invl, fb = cb * invl;

        const int t = qt * 128 + wl * 32 + ql;
        unsigned short* crow = ctx + ((size_t)b * T_SEQ + t) * D_MODEL + h * HDIM;
        #pragma unroll
        for (int r4 = 0; r4 < 4; ++r4) {
            const int d0 = 8 * r4 + 4 * hi;
            ushort4 w;
            w.x = f2bf(o0[4 * r4 + 0] * fa + pa0[4 * r4 + 0] * fb);
            w.y = f2bf(o0[4 * r4 + 1] * fa + pa0[4 * r4 + 1] * fb);
            w.z = f2bf(o0[4 * r4 + 2] * fa + pa0[4 * r4 + 2] * fb);
            w.w = f2bf(o0[4 * r4 + 3] * fa + pa0[4 * r4 + 3] * fb);
            *reinterpret_cast<ushort4*>(crow + d0) = w;
            w.x = f2bf(o1[4 * r4 + 0] * fa + pb0[4 * r4 + 0] * fb);
            w.y = f2bf(o1[4 * r4 + 1] * fa + pb0[4 * r4 + 1] * fb);
            w.z = f2bf(o1[4 * r4 + 2] * fa + pb0[4 * r4 + 2] * fb);
            w.w = f2bf(o1[4 * r4 + 3] * fa + pb0[4 * r4 + 3] * fb);
            *reinterpret_cast<ushort4*>(crow + 32 + d0) = w;
        }
    }
}

extern "C" void kernel_launch(void* const* d_in, const int* in_sizes, int n_in,
                              void* d_out, int out_size, void* d_ws, size_t ws_size,
                              hipStream_t stream) {
    const float* x    = (const float*)d_in[0];
    const float* Wqkv = (const float*)d_in[1];
    const float* bqkv = (const float*)d_in[2];
    const float* Wout = (const float*)d_in[3];
    const float* bout = (const float*)d_in[4];
    float* out = (float*)d_out;

    char* ws = (char*)d_ws;
    unsigned short* xb    = (unsigned short*)(ws);                 // 8 MB
    unsigned short* wqkvT = (unsigned short*)(ws + 8388608);       // 6 MB  [3072][1024]
    unsigned short* woutT = (unsigned short*)(ws + 14680064);      // 2 MB  [1024][1024]
    unsigned short* qkv   = (unsigned short*)(ws + 16777216);      // 24 MB (Q, K, V^T)
    unsigned short* ctx   = (unsigned short*)(ws + 41943040);      // 8 MB

    // fused prep: x convert (4096 blks) + Wqkv^T (768) + Wout^T (256)
    prep<<<5120, 256, 0, stream>>>(x, xb, Wqkv, wqkvT, Wout, woutT);

    // gemm0: 1-D grid, 24*32 = 768 blocks (%8==0); V written as sigma-V^T directly
    gemm128<0><<<768, 256, 0, stream>>>(xb, wqkvT, bqkv, qkv, nullptr,
                                        BATCH * T_SEQ, 3 * D_MODEL, D_MODEL);

    dim3 g2(T_SEQ / 128, NHEADS, BATCH);
    attn32<<<g2, 512, 0, stream>>>(qkv,
                                   qkv + (size_t)QKVSZ,
                                   qkv + (size_t)2 * QKVSZ,
                                   ctx);

    // gemm1: 1-D grid, 8*32 = 256 blocks (%8==0)
    gemm128<1><<<256, 256, 0, stream>>>(ctx, woutT, bout, nullptr, out,
                                        BATCH * T_SEQ, D_MODEL, D_MODEL);
}